// Round 6
// baseline (847.325 us; speedup 1.0000x reference)
//
#include <hip/hip_runtime.h>
#include <hip/hip_bf16.h>
#include <math.h>

typedef unsigned short u16;
typedef short bf16x8 __attribute__((ext_vector_type(8)));
typedef float f32x4 __attribute__((ext_vector_type(4)));

#define Bz 64
#define Tt 4096
#define Cin 64
#define K1c 128
#define Hh 96
#define T2 1024
#define G4 384
#define NC 109

#define MFMA16(a, b, c) __builtin_amdgcn_mfma_f32_16x16x32_bf16(a, b, c, 0, 0, 0)

__device__ __forceinline__ float bf2f(u16 v) {
  union { unsigned int u; float f; } x; x.u = ((unsigned int)v) << 16; return x.f;
}
__device__ __forceinline__ u16 f2bf(float f) {
  union { unsigned int u; float f; } x; x.f = f;
  unsigned int u = x.u;
  unsigned int r = u + 0x7fff + ((u >> 16) & 1);
  return (u16)(r >> 16);
}
__device__ __forceinline__ float dpp_xor1(float x) {
  int r = __builtin_amdgcn_mov_dpp(__float_as_int(x), 0xB1, 0xF, 0xF, true);
  return __int_as_float(r);
}
__device__ __forceinline__ float dpp_xor2(float x) {
  int r = __builtin_amdgcn_mov_dpp(__float_as_int(x), 0x4E, 0xF, 0xF, true);
  return __int_as_float(r);
}

// ---------------- K0: weight packing + BN folding ----------------
__global__ void k_prep(const float* __restrict__ w1, const float* __restrict__ cb1,
                       const float* __restrict__ g1, const float* __restrict__ b1,
                       const float* __restrict__ m1, const float* __restrict__ v1,
                       const float* __restrict__ w2, const float* __restrict__ cb2,
                       const float* __restrict__ g2, const float* __restrict__ b2,
                       const float* __restrict__ m2, const float* __restrict__ v2,
                       const float* __restrict__ wr, const float* __restrict__ cbr,
                       const float* __restrict__ gr, const float* __restrict__ br,
                       const float* __restrict__ mr, const float* __restrict__ vr,
                       const float* __restrict__ wx, const float* __restrict__ sbia,
                       u16* __restrict__ w1b, u16* __restrict__ w2b,
                       u16* __restrict__ wrb, float* __restrict__ wxT,
                       float* __restrict__ bperm,
                       float* __restrict__ al1, float* __restrict__ be1,
                       float* __restrict__ al2, float* __restrict__ be2,
                       float* __restrict__ alr, float* __restrict__ ber)
{
  int tid = blockIdx.x * blockDim.x + threadIdx.x;
  int nth = gridDim.x * blockDim.x;
  // w1b[o*448 + kt*64 + c] = bf16(w1[o][c][kt])
  for (int idx = tid; idx < 128 * 448; idx += nth) {
    int o = idx / 448, k = idx % 448;
    int kt = k >> 6, c = k & 63;
    w1b[idx] = f2bf(w1[(o * 64 + c) * 7 + kt]);
  }
  // w2b[o*384 + kk*128 + c] = bf16(w2[o][c][kk])
  for (int idx = tid; idx < 96 * 384; idx += nth) {
    int o = idx / 384, k = idx % 384;
    int kk = k >> 7, c = k & 127;
    w2b[idx] = f2bf(w2[(o * 128 + c) * 3 + kk]);
  }
  // wrb[o*128 + c] = bf16(wr[o][c])
  for (int idx = tid; idx < 96 * 128; idx += nth) {
    wrb[idx] = f2bf(wr[idx]);
  }
  // wxT[h*384 + (ch*4+g)] = wx[g*96+ch][h]  (permuted: ch-major gate packing)
  for (int idx = tid; idx < 96 * 384; idx += nth) {
    int c = idx % 384, h = idx / 384;
    int ch = c >> 2, g = c & 3;
    wxT[idx] = wx[((size_t)(g * 96 + ch)) * 96 + h];
  }
  // bperm[ch*4+g] = sbia[g*96+ch]
  for (int c = tid; c < 384; c += nth) {
    int ch = c >> 2, g = c & 3;
    bperm[c] = sbia[g * 96 + ch];
  }
  for (int o = tid; o < 128; o += nth) {
    float a = g1[o] / sqrtf(v1[o] + 1e-5f);
    al1[o] = a; be1[o] = b1[o] + (cb1[o] - m1[o]) * a;
  }
  for (int o = tid; o < 96; o += nth) {
    float a = g2[o] / sqrtf(v2[o] + 1e-5f);
    al2[o] = a; be2[o] = b2[o] + (cb2[o] - m2[o]) * a;
    float ar = gr[o] / sqrtf(vr[o] + 1e-5f);
    alr[o] = ar; ber[o] = br[o] + (cbr[o] - mr[o]) * ar;
  }
}

// ---------------- K1: conv1 MFMA implicit GEMM (unchanged) ----------------
__launch_bounds__(256, 2)
__global__ void k_conv1(const float* __restrict__ x, const u16* __restrict__ w1b,
                        const float* __restrict__ al1, const float* __restrict__ be1,
                        u16* __restrict__ out1)
{
  __shared__ __align__(16) u16 xs[134 * 72];
  int tid = threadIdx.x;
  int b = blockIdx.y;
  int t0 = blockIdx.x * 128;
  const float* xb = x + (size_t)b * Tt * Cin;

  for (int idx = tid; idx < 134 * 16; idx += 256) {
    int row = idx >> 4, c4 = (idx & 15) << 2;
    int gt = t0 - 3 + row;
    float4 v = make_float4(0.f, 0.f, 0.f, 0.f);
    if (gt >= 0 && gt < Tt) v = *(const float4*)(xb + (size_t)gt * 64 + c4);
    ushort4 s;
    s.x = f2bf(v.x); s.y = f2bf(v.y); s.z = f2bf(v.z); s.w = f2bf(v.w);
    *(ushort4*)(xs + row * 72 + c4) = s;
  }
  __syncthreads();

  int l = tid & 63;
  int wid = tid >> 6;
  int wm = wid >> 1, wn = wid & 1;
  int lr = l & 15, g = l >> 4;

  f32x4 acc[4][4];
#pragma unroll
  for (int i = 0; i < 4; i++)
#pragma unroll
    for (int j = 0; j < 4; j++) acc[i][j] = (f32x4){0.f, 0.f, 0.f, 0.f};

  const u16* wbase = w1b + (size_t)(wn * 64 + lr) * 448;

  for (int s = 0; s < 14; ++s) {
    int kt = s >> 1;
    int cofs = ((s & 1) << 5) + (g << 3);
    const u16* xrow = xs + (wm * 64 + lr + kt) * 72 + cofs;
    bf16x8 a0 = *(const bf16x8*)(xrow);
    bf16x8 a1 = *(const bf16x8*)(xrow + 16 * 72);
    bf16x8 a2 = *(const bf16x8*)(xrow + 32 * 72);
    bf16x8 a3 = *(const bf16x8*)(xrow + 48 * 72);
    int ko = (s << 5) + (g << 3);
    bf16x8 b0 = *(const bf16x8*)(wbase + ko);
    bf16x8 b1 = *(const bf16x8*)(wbase + 16 * 448 + ko);
    bf16x8 b2 = *(const bf16x8*)(wbase + 32 * 448 + ko);
    bf16x8 b3 = *(const bf16x8*)(wbase + 48 * 448 + ko);
    acc[0][0] = MFMA16(a0, b0, acc[0][0]);
    acc[0][1] = MFMA16(a0, b1, acc[0][1]);
    acc[0][2] = MFMA16(a0, b2, acc[0][2]);
    acc[0][3] = MFMA16(a0, b3, acc[0][3]);
    acc[1][0] = MFMA16(a1, b0, acc[1][0]);
    acc[1][1] = MFMA16(a1, b1, acc[1][1]);
    acc[1][2] = MFMA16(a1, b2, acc[1][2]);
    acc[1][3] = MFMA16(a1, b3, acc[1][3]);
    acc[2][0] = MFMA16(a2, b0, acc[2][0]);
    acc[2][1] = MFMA16(a2, b1, acc[2][1]);
    acc[2][2] = MFMA16(a2, b2, acc[2][2]);
    acc[2][3] = MFMA16(a2, b3, acc[2][3]);
    acc[3][0] = MFMA16(a3, b0, acc[3][0]);
    acc[3][1] = MFMA16(a3, b1, acc[3][1]);
    acc[3][2] = MFMA16(a3, b2, acc[3][2]);
    acc[3][3] = MFMA16(a3, b3, acc[3][3]);
  }

  int colb = wn * 64 + lr;
  int rowb = t0 + wm * 64 + (l >> 4) * 4;
#pragma unroll
  for (int nf = 0; nf < 4; nf++) {
    int col = colb + nf * 16;
    float A = al1[col], Bt = be1[col];
#pragma unroll
    for (int mf = 0; mf < 4; mf++) {
      int row = rowb + mf * 16;
#pragma unroll
      for (int r = 0; r < 4; r++) {
        float v = acc[mf][nf][r];
        v = fmaxf(v * A + Bt, 0.f);
        out1[((size_t)b * Tt + row + r) * 128 + col] = f2bf(v);
      }
    }
  }
}

// ---------------- K2: conv2 MFMA implicit GEMM + fused residual (unchanged) ----------------
__launch_bounds__(256, 4)
__global__ void k_conv2(const u16* __restrict__ out1, const u16* __restrict__ w2b,
                        const u16* __restrict__ wrb,
                        const float* __restrict__ al2, const float* __restrict__ be2,
                        const float* __restrict__ alr, const float* __restrict__ ber,
                        float* __restrict__ seq)
{
  int tid = threadIdx.x;
  int b = blockIdx.y;
  int t20 = blockIdx.x * 64;
  int l = tid & 63;
  int wid = tid >> 6;
  int wm = wid >> 1, wn = wid & 1;    // wave tile 32 x 48
  int lr = l & 15, g = l >> 4;

  f32x4 acc[2][3], accr[2][3];
#pragma unroll
  for (int i = 0; i < 2; i++)
#pragma unroll
    for (int j = 0; j < 3; j++) {
      acc[i][j] = (f32x4){0.f, 0.f, 0.f, 0.f};
      accr[i][j] = (f32x4){0.f, 0.f, 0.f, 0.f};
    }

  const u16* ob = out1 + (size_t)b * Tt * 128;
  int colb = wn * 48 + lr;

#pragma unroll
  for (int f = 0; f < 12; f++) {
    int kk = f >> 2;
    int c = ((f & 3) << 5) + (g << 3);
    bf16x8 a[2];
#pragma unroll
    for (int mf = 0; mf < 2; mf++) {
      int t2 = t20 + wm * 32 + mf * 16 + lr;
      int gt = 4 * t2 + kk - 1;
      if (gt >= 0)
        a[mf] = *(const bf16x8*)(ob + (size_t)gt * 128 + c);
      else
        a[mf] = (bf16x8){0, 0, 0, 0, 0, 0, 0, 0};
    }
#pragma unroll
    for (int nf = 0; nf < 3; nf++) {
      int col = colb + nf * 16;
      bf16x8 bb = *(const bf16x8*)(w2b + (size_t)col * 384 + (f << 5) + (g << 3));
      acc[0][nf] = MFMA16(a[0], bb, acc[0][nf]);
      acc[1][nf] = MFMA16(a[1], bb, acc[1][nf]);
    }
    if (kk == 1) {
#pragma unroll
      for (int nf = 0; nf < 3; nf++) {
        int col = colb + nf * 16;
        bf16x8 br = *(const bf16x8*)(wrb + (size_t)col * 128 + ((f & 3) << 5) + (g << 3));
        accr[0][nf] = MFMA16(a[0], br, accr[0][nf]);
        accr[1][nf] = MFMA16(a[1], br, accr[1][nf]);
      }
    }
  }

  int rowb = t20 + wm * 32 + (l >> 4) * 4;
#pragma unroll
  for (int nf = 0; nf < 3; nf++) {
    int col = colb + nf * 16;
    float A = al2[col], Bt = be2[col];
    float Ar = alr[col], Br = ber[col];
#pragma unroll
    for (int mf = 0; mf < 2; mf++) {
      int row = rowb + mf * 16;
#pragma unroll
      for (int r = 0; r < 4; r++) {
        float v = fmaxf(acc[mf][nf][r] * A + Bt, 0.f) + accr[mf][nf][r] * Ar + Br;
        seq[((size_t)b * T2 + row + r) * 96 + col] = v;
      }
    }
  }
}

// ---------------- K3: pre = seq @ wxT + bias, fp32, zero-LDS (unchanged) ----------------
__launch_bounds__(256)
__global__ void k_pre(const float* __restrict__ seq, const float* __restrict__ wxT,
                      const float* __restrict__ bias, float* __restrict__ pre)
{
  int tid = threadIdx.x;
  int b = blockIdx.z, nt = blockIdx.y, t20 = blockIdx.x * 128;
  int g0 = nt * 128;
  int lane32 = tid & 31, col4 = lane32 * 4;
  int trow = (tid >> 5) * 16;

  const float* sb = seq + ((size_t)b * T2 + t20 + trow) * 96;
  const float* wb = wxT + g0 + col4;

  f32x4 acc[16];
#pragma unroll
  for (int r = 0; r < 16; r++) acc[r] = (f32x4){0.f, 0.f, 0.f, 0.f};

  for (int kb = 0; kb < 96; kb += 4) {
    f32x4 bw0 = *(const f32x4*)(wb + (size_t)(kb + 0) * 384);
    f32x4 bw1 = *(const f32x4*)(wb + (size_t)(kb + 1) * 384);
    f32x4 bw2 = *(const f32x4*)(wb + (size_t)(kb + 2) * 384);
    f32x4 bw3 = *(const f32x4*)(wb + (size_t)(kb + 3) * 384);
#pragma unroll
    for (int r = 0; r < 16; r++) {
      f32x4 av = *(const f32x4*)(sb + (size_t)r * 96 + kb);
      acc[r] += av.x * bw0;
      acc[r] += av.y * bw1;
      acc[r] += av.z * bw2;
      acc[r] += av.w * bw3;
    }
  }

  f32x4 b4 = *(const f32x4*)(bias + g0 + col4);
  float* pb = pre + ((size_t)b * T2 + t20 + trow) * 384 + g0 + col4;
#pragma unroll
  for (int r = 0; r < 16; r++) {
    *(f32x4*)(pb + (size_t)r * 384) = acc[r] + b4;
  }
}

// ---------------- K4: sLSTM recurrence v4 — 8 waves for latency overlap ----------------
// 512 threads = 8 waves (2/SIMD). One block per batch.
// Wave w owns channels [12w, 12w+12) -> 48 rows (row = chl*4 + gate).
// Lane (q=lane>>2, j=lane&3): rows 3q..3q+2, K-slice [24j, 24j+24).
// 72 FMA/lane; 2 waves/SIMD keep the same 288-cyc VALU floor but overlap
// each other's DS/TRANS/barrier latencies.
// Publish: one ds_write_b32 (lane j<3 writes row 3q+j), gate lanes (<12)
// ds_read_b128 their channel's 4 rows (intra-wave DS FIFO, no barrier).
// One __syncthreads per step for the h broadcast (ping-pong hbuf).
__launch_bounds__(512)
__global__ void k_slstm(const float* __restrict__ pre, const float* __restrict__ wh,
                        float* __restrict__ hsum)
{
  __shared__ __align__(16) float hbuf[2][96];
  __shared__ __align__(16) float pwbuf[8][48];
  int tid = threadIdx.x;
  int b = blockIdx.x;
  int w = tid >> 6;          // 0..7
  int lane = tid & 63;
  int q = lane >> 2, j = lane & 3;

  // weights: rows r = 3q+a (a<3), global gate row (g*96 + ch), K-slice j*24
  float4 wq[3][6];
#pragma unroll
  for (int a = 0; a < 3; a++) {
    int r = 3 * q + a;
    int chl = r >> 2, g = r & 3;
    int ch = 12 * w + chl;
    const float4* wrow = (const float4*)(wh + ((size_t)(g * 96 + ch)) * 96 + j * 24);
#pragma unroll
    for (int kq = 0; kq < 6; kq++) wq[a][kq] = wrow[kq];
  }

  bool gl = (lane < 12);
  float c = 0.f, n = 0.f, m = 0.f, hs = 0.f;
  if (tid < 96) hbuf[0][tid] = 0.f;
  __syncthreads();

  // px prefetch (gate lanes): float4 (z,i,f,o) for ch = 12w+lane
  const float4* pxp = (const float4*)(pre + (size_t)b * T2 * G4) + (12 * w + lane);
  float4 pxA = make_float4(0, 0, 0, 0), pxB = pxA;
  if (gl) { pxA = pxp[0]; pxB = pxp[96]; }

  const float L2E = 1.44269504f;
  int p = 0;
  for (int t = 0; t < T2; t++) {
    float4 pxN = make_float4(0, 0, 0, 0);
    if (gl) {
      int tn = t + 2 < T2 ? t + 2 : T2 - 1;
      pxN = pxp[(size_t)tn * 96];
    }
    // h slice: 24 floats at [24j, 24j+24) — same addr within j-group (broadcast)
    float4 hq[6];
#pragma unroll
    for (int kq = 0; kq < 6; kq++) hq[kq] = *(const float4*)(&hbuf[p][j * 24 + kq * 4]);

    float s0 = 0.f, s1 = 0.f, s2 = 0.f;
#pragma unroll
    for (int kq = 0; kq < 6; kq++) {
      s0 += hq[kq].x * wq[0][kq].x; s0 += hq[kq].y * wq[0][kq].y;
      s0 += hq[kq].z * wq[0][kq].z; s0 += hq[kq].w * wq[0][kq].w;
      s1 += hq[kq].x * wq[1][kq].x; s1 += hq[kq].y * wq[1][kq].y;
      s1 += hq[kq].z * wq[1][kq].z; s1 += hq[kq].w * wq[1][kq].w;
      s2 += hq[kq].x * wq[2][kq].x; s2 += hq[kq].y * wq[2][kq].y;
      s2 += hq[kq].z * wq[2][kq].z; s2 += hq[kq].w * wq[2][kq].w;
    }
    // quad reduce over j (VALU-only DPP)
    s0 += dpp_xor1(s0); s0 += dpp_xor2(s0);
    s1 += dpp_xor1(s1); s1 += dpp_xor2(s1);
    s2 += dpp_xor1(s2); s2 += dpp_xor2(s2);

    // one ds_write_b32: lane j<3 publishes row 3q+j
    float wv = (j == 0) ? s0 : ((j == 1) ? s1 : s2);
    if (j < 3) pwbuf[w][3 * q + j] = wv;
    asm volatile("" ::: "memory");  // intra-wave DS FIFO order
    if (gl) {
      float4 pa = *(const float4*)(&pwbuf[w][lane * 4]);
      float zp = pa.x + pxA.x, ip = pa.y + pxA.y;
      float fp = pa.z + pxA.z, op = pa.w + pxA.w;
      float zc = fminf(fmaxf(zp, -30.f), 30.f);
      float ez = exp2f(zc * (2.f * L2E));
      float z = 1.f - 2.f * __builtin_amdgcn_rcpf(ez + 1.f);
      float oc = fminf(fmaxf(op, -30.f), 30.f);
      float o = __builtin_amdgcn_rcpf(1.f + exp2f(-oc * L2E));
      float mn = fmaxf(fp + m, ip);
      float iv = exp2f((ip - mn) * L2E);
      float fv = exp2f((fp + m - mn) * L2E);
      c = fv * c + iv * z;
      n = fv * n + iv;
      m = mn;
      float h = o * c * __builtin_amdgcn_rcpf(fmaxf(n, 1.f));
      hs += h;
      hbuf[p ^ 1][12 * w + lane] = h;
    }
    pxA = pxB; pxB = pxN;
    __syncthreads();
    p ^= 1;
  }
  if (gl) hsum[b * 96 + 12 * w + lane] = hs * (1.f / 1024.f);
}

// ---------------- K5: head (unchanged) ----------------
__launch_bounds__(128)
__global__ void k_head(const float* __restrict__ hsum, const float* __restrict__ fc1w,
                       const float* __restrict__ fc1b, const float* __restrict__ fc2w,
                       const float* __restrict__ fc2b, float* __restrict__ out)
{
  __shared__ float p[96];
  __shared__ float z1[128];
  int tid = threadIdx.x, b = blockIdx.x;
  if (tid < 96) p[tid] = hsum[b * 96 + tid];
  __syncthreads();
  {
    float a = fc1b[tid];
    const float* wr = fc1w + tid * 96;
    for (int h = 0; h < 96; h++) a += p[h] * wr[h];
    z1[tid] = fmaxf(a, 0.f);
  }
  __syncthreads();
  if (tid < NC) {
    float a = fc2b[tid];
    const float* wr = fc2w + tid * 128;
    for (int j = 0; j < 128; j++) a += z1[j] * wr[j];
    out[b * NC + tid] = a;
  }
}

extern "C" void kernel_launch(void* const* d_in, const int* in_sizes, int n_in,
                              void* d_out, int out_size, void* d_ws, size_t ws_size,
                              hipStream_t stream)
{
  const float* x    = (const float*)d_in[0];
  const float* w1   = (const float*)d_in[1];
  const float* cb1  = (const float*)d_in[2];
  const float* g1   = (const float*)d_in[3];
  const float* b1   = (const float*)d_in[4];
  const float* m1   = (const float*)d_in[5];
  const float* v1   = (const float*)d_in[6];
  const float* w2   = (const float*)d_in[7];
  const float* cb2  = (const float*)d_in[8];
  const float* g2   = (const float*)d_in[9];
  const float* b2   = (const float*)d_in[10];
  const float* m2   = (const float*)d_in[11];
  const float* v2   = (const float*)d_in[12];
  const float* wr   = (const float*)d_in[13];
  const float* cbr  = (const float*)d_in[14];
  const float* gr   = (const float*)d_in[15];
  const float* br   = (const float*)d_in[16];
  const float* mr   = (const float*)d_in[17];
  const float* vr   = (const float*)d_in[18];
  const float* wx   = (const float*)d_in[19];
  const float* wh   = (const float*)d_in[20];
  const float* sbia = (const float*)d_in[21];
  const float* fc1w = (const float*)d_in[22];
  const float* fc1b = (const float*)d_in[23];
  const float* fc2w = (const float*)d_in[24];
  const float* fc2b = (const float*)d_in[25];

  char* ws = (char*)d_ws;
  size_t off = 0;
  auto alloc = [&](size_t bytes) -> void* {
    void* p = (void*)(ws + off);
    off = (off + bytes + 255) & ~((size_t)255);
    return p;
  };
  u16*   out1 = (u16*)  alloc((size_t)Bz * Tt * K1c * 2);   // 67.1 MB
  float* seq  = (float*)alloc((size_t)Bz * T2 * Hh * 4);    // 25.2 MB
  float* pre  = (float*)alloc((size_t)Bz * T2 * G4 * 4);    // 100.7 MB
  u16*   w1b  = (u16*)  alloc(448 * 128 * 2);
  u16*   w2b  = (u16*)  alloc(96 * 384 * 2);
  u16*   wrb  = (u16*)  alloc(96 * 128 * 2);
  float* wxT  = (float*)alloc(96 * 384 * 4);
  float* bperm= (float*)alloc(384 * 4);
  float* al1  = (float*)alloc(128 * 4);
  float* be1  = (float*)alloc(128 * 4);
  float* al2  = (float*)alloc(96 * 4);
  float* be2  = (float*)alloc(96 * 4);
  float* alr  = (float*)alloc(96 * 4);
  float* ber  = (float*)alloc(96 * 4);
  float* hsum = (float*)alloc((size_t)Bz * Hh * 4);
  (void)ws_size; (void)in_sizes; (void)n_in; (void)out_size;

  k_prep<<<dim3(224), dim3(256), 0, stream>>>(
      w1, cb1, g1, b1, m1, v1, w2, cb2, g2, b2, m2, v2,
      wr, cbr, gr, br, mr, vr, wx, sbia,
      w1b, w2b, wrb, wxT, bperm, al1, be1, al2, be2, alr, ber);

  k_conv1<<<dim3(Tt / 128, Bz), dim3(256), 0, stream>>>(x, w1b, al1, be1, out1);

  k_conv2<<<dim3(T2 / 64, Bz), dim3(256), 0, stream>>>(out1, w2b, wrb, al2, be2, alr, ber, seq);

  k_pre<<<dim3(T2 / 128, 3, Bz), dim3(256), 0, stream>>>(seq, wxT, bperm, pre);

  k_slstm<<<dim3(Bz), dim3(512), 0, stream>>>(pre, wh, hsum);

  k_head<<<dim3(Bz), dim3(128), 0, stream>>>(hsum, fc1w, fc1b, fc2w, fc2b, (float*)d_out);
}